// Round 9
// baseline (1288.579 us; speedup 1.0000x reference)
//
#include <hip/hip_runtime.h>
#include <hip/hip_bf16.h>
#include <math.h>

// Problem constants (N_WAY=64, K_SHOT=5, Q_QUERY=128, D_FEAT=128)
#define M     8192      // n*q query rows
#define D     128       // feature dim
#define NCLS  64        // n classes
#define KSHOT 5
#define XROW  133       // (k+q) rows per class in x
#define KTOP  9
#define EPSV  1e-8f

// k2: 256 thr, 128i x 128j tile, 8x8 acc/thread (1 B LDS per lane-FMA --
// R7's 4x4 needed 2 B/FMA and was LDS-BW-bound at 506us). k-chunks of 32,
// single-buffered (42.5 KB LDS -> 3 blocks/CU = 3 waves/SIMD). Per-row top9
// lives in LDS so VGPR peak ~110 < the 128 clamp (R2-R6 lesson).
#define TPB   256
#define BI    128           // i rows per block
#define SJ    16            // j splits
#define JPB   (M / SJ)      // 512 j per block
#define TJ    128           // j per tile
#define NJT   (JPB / TJ)    // 4 j-tiles
#define NKC   4             // k chunks of 32
#define NPART SJ            // 16 partial top-9 lists per i-row
// LDS float2-grain chunk layout: f2elem[kp*128 + prow], prow(r) = (r>>3)|((r&7)<<4)
// sims overlay: [64 rows][stride 130 floats] = 8320 floats = whole chunk region

// ---------------------------------------------------------------------------
// register-resident top-9 with (value desc, index asc) tie-break, matching
// jax.lax.top_k set semantics. Fully unrolled -> static indexing -> VGPRs.
__device__ __forceinline__ void top9_insert(float (&kv)[KTOP], int (&ki)[KTOP],
                                            float v, int j) {
  if (v > kv[KTOP - 1] || (v == kv[KTOP - 1] && j < ki[KTOP - 1])) {
    float cv = v; int cj = j;
#pragma unroll
    for (int t = 0; t < KTOP; ++t) {
      bool b = (cv > kv[t]) || (cv == kv[t] && cj < ki[t]);
      float tv = kv[t]; int ti_ = ki[t];
      kv[t] = b ? cv : tv;  ki[t] = b ? cj : ti_;
      cv   = b ? tv : cv;   cj   = b ? ti_ : cj;
    }
  }
}

// ---------------------------------------------------------------------------
__global__ void k0_proto(const float* __restrict__ x, float* __restrict__ protnT) {
  int c = blockIdx.x;
  int lane = threadIdx.x;
  const float* base = x + (size_t)(c * XROW) * D;
  float a0 = 0.f, a1 = 0.f;
#pragma unroll
  for (int s = 0; s < KSHOT; ++s) {
    a0 += base[s * D + lane];
    a1 += base[s * D + 64 + lane];
  }
  a0 *= 0.2f; a1 *= 0.2f;
  float ss = a0 * a0 + a1 * a1;
#pragma unroll
  for (int off = 1; off < 64; off <<= 1) ss += __shfl_xor(ss, off);
  float rn = 1.0f / fmaxf(sqrtf(ss), EPSV);
  protnT[lane * NCLS + c]        = a0 * rn;
  protnT[(lane + 64) * NCLS + c] = a1 * rn;
}

// ---------------------------------------------------------------------------
__global__ void k1_qnorm(const float* __restrict__ x, float* __restrict__ qn) {
  int lane = threadIdx.x & 63;
  int wv = threadIdx.x >> 6;
  int r = blockIdx.x * 4 + wv;
  int xr = (r >> 7) * XROW + KSHOT + (r & 127);
  const float* src = x + (size_t)xr * D;
  float v0 = src[lane], v1 = src[64 + lane];
  float ss = v0 * v0 + v1 * v1;
#pragma unroll
  for (int off = 1; off < 64; off <<= 1) ss += __shfl_xor(ss, off);
  float rn = 1.0f / fmaxf(sqrtf(ss), EPSV);
  qn[(size_t)r * D + lane]      = v0 * rn;
  qn[(size_t)r * D + 64 + lane] = v1 * rn;
}

// ---------------------------------------------------------------------------
// stage one 128-row x 32-k chunk, float2-grain transposed: f2[kp*128 + prow].
// Thread t loads 16 consecutive k (4 float4) of row r(t) and writes 8 float2s
// at prow = t&127 (prow(r(t)) == t&127, proven bijection).
__device__ __forceinline__ void stage_chunk(float* dstf, const float* __restrict__ src,
                                            int prow, int seg) {
  float4 v0 = ((const float4*)src)[0];
  float4 v1 = ((const float4*)src)[1];
  float4 v2 = ((const float4*)src)[2];
  float4 v3 = ((const float4*)src)[3];
  float2* d = (float2*)dstf;
  int kp0 = seg * 8;
  d[(kp0 + 0) * 128 + prow] = make_float2(v0.x, v0.y);
  d[(kp0 + 1) * 128 + prow] = make_float2(v0.z, v0.w);
  d[(kp0 + 2) * 128 + prow] = make_float2(v1.x, v1.y);
  d[(kp0 + 3) * 128 + prow] = make_float2(v1.z, v1.w);
  d[(kp0 + 4) * 128 + prow] = make_float2(v2.x, v2.y);
  d[(kp0 + 5) * 128 + prow] = make_float2(v2.z, v2.w);
  d[(kp0 + 6) * 128 + prow] = make_float2(v3.x, v3.y);
  d[(kp0 + 7) * 128 + prow] = make_float2(v3.z, v3.w);
}

// ---------------------------------------------------------------------------
__global__ __launch_bounds__(TPB) void
k2_topk(const float* __restrict__ qn, float* __restrict__ pkv, int* __restrict__ pki) {
  // Ac floats [0,4096), Bc [4096,8192); sims overlay [0,8320): 64 rows x 130
  __shared__ __align__(16) float buf[8320];
  __shared__ float tkv[BI * KTOP];
  __shared__ int   tki[BI * KTOP];

  const int tid  = threadIdx.x;
  const int ib   = blockIdx.x >> 4;       // 64 i-blocks
  const int js   = blockIdx.x & (SJ - 1); // 16 j-splits
  const int ibase = ib * BI;
  const int jsbase = js * JPB;

  const int tig = tid >> 4;               // i-group: rows 8*tig..+7
  const int tjg = tid & 15;               // j-group: cols 8*tjg..+7
  const int srow = ((tid & 15) << 3) | ((tid >> 4) & 7);  // stage row r(t)
  const int prow = tid & 127;             // stage slot (== prow(r(t)))
  const int seg  = tid >> 7;              // stage k-half

  // init LDS-resident per-row top9 lists
  if (tid < BI) {
#pragma unroll
    for (int t = 0; t < KTOP; ++t) {
      tkv[tid * KTOP + t] = -INFINITY;
      tki[tid * KTOP + t] = 0x7fffffff;
    }
  }

  for (int jt = 0; jt < NJT; ++jt) {
    const int jbase = jsbase + jt * TJ;

    float acc[8][8];
#pragma unroll
    for (int ri = 0; ri < 8; ++ri)
#pragma unroll
      for (int rj = 0; rj < 8; ++rj) acc[ri][rj] = 0.f;

    for (int kc = 0; kc < NKC; ++kc) {
      __syncthreads();   // previous readers of buf are done (also covers init)
      stage_chunk(buf,        qn + (size_t)(ibase + srow) * D + kc * 32 + seg * 16, prow, seg);
      stage_chunk(buf + 4096, qn + (size_t)(jbase + srow) * D + kc * 32 + seg * 16, prow, seg);
      __syncthreads();

      const float2* Af = (const float2*)buf + tig;
      const float2* Bf = (const float2*)(buf + 4096) + tjg;
      for (int kp = 0; kp < 16; ++kp) {     // no unroll: 16 loads/iter self-hide
        float2 a[8], b[8];
#pragma unroll
        for (int r = 0; r < 8; ++r) {
          a[r] = Af[kp * 128 + r * 16];
          b[r] = Bf[kp * 128 + r * 16];
        }
#pragma unroll
        for (int ri = 0; ri < 8; ++ri)
#pragma unroll
          for (int rj = 0; rj < 8; ++rj)
            acc[ri][rj] += a[ri].x * b[rj].x + a[ri].y * b[rj].y;
      }
    }

    // ---- scan in two 64-row halves (sims overlay = whole chunk region) ----
#pragma unroll
    for (int h = 0; h < 2; ++h) {
      __syncthreads();                      // compute / previous scan done
      if ((tid >> 7) == h) {                // this half's threads write sims
        float2* sf = (float2*)buf;
        int lrow = (tig & 7) * 8;           // local row base 0..56
#pragma unroll
        for (int rr = 0; rr < 8; ++rr) {
#pragma unroll
          for (int p = 0; p < 4; ++p)
            sf[(size_t)(lrow + rr) * 65 + tjg * 4 + p] =
                make_float2(acc[rr][2 * p], acc[rr][2 * p + 1]);
        }
      }
      __syncthreads();
      if (tid < 64) {                       // one thread per row scans 128 j
        int grow = h * 64 + tid;            // local row 0..127
        float kv[KTOP]; int ki[KTOP];
#pragma unroll
        for (int t = 0; t < KTOP; ++t) {
          kv[t] = tkv[grow * KTOP + t];
          ki[t] = tki[grow * KTOP + t];
        }
        const float2* sf = (const float2*)buf + (size_t)tid * 65;
        for (int m = 0; m < 64; ++m) {
          float2 s = sf[m];
          top9_insert(kv, ki, s.x, jbase + 2 * m);
          top9_insert(kv, ki, s.y, jbase + 2 * m + 1);
        }
#pragma unroll
        for (int t = 0; t < KTOP; ++t) {
          tkv[grow * KTOP + t] = kv[t];
          tki[grow * KTOP + t] = ki[t];
        }
      }
    }
  }

  __syncthreads();
  if (tid < BI) {                           // write this block's partial lists
    int i = ibase + tid;
    size_t base = ((size_t)i * NPART + js) * KTOP;
#pragma unroll
    for (int t = 0; t < KTOP; ++t) {
      pkv[base + t] = tkv[tid * KTOP + t];
      pki[base + t] = tki[tid * KTOP + t];
    }
  }
}

// ---------------------------------------------------------------------------
// k_merge: per row, merge the 16 partial top-9 lists (disjoint j-ranges).
__global__ void k_merge(const float* __restrict__ pkv, const int* __restrict__ pki,
                        float* __restrict__ kval, int* __restrict__ kidx) {
  int i = blockIdx.x * blockDim.x + threadIdx.x;
  float kv[KTOP]; int ki[KTOP];
#pragma unroll
  for (int t = 0; t < KTOP; ++t) { kv[t] = -INFINITY; ki[t] = 0x7fffffff; }
  const float* pv = pkv + (size_t)i * NPART * KTOP;
  const int*   pi = pki + (size_t)i * NPART * KTOP;
  for (int t = 0; t < NPART * KTOP; ++t) top9_insert(kv, ki, pv[t], pi[t]);
#pragma unroll
  for (int t = 0; t < KTOP; ++t) {
    kval[(size_t)i * KTOP + t] = kv[t];
    kidx[(size_t)i * KTOP + t] = ki[t];
  }
}

// ---------------------------------------------------------------------------
// k3: mutual mask + softmax over <=9 entries + adapted query + normalize +
// project on normalized prototypes, scale by tao. One wave per query row.
__global__ void k3_out(const float* __restrict__ x, const float* __restrict__ kval,
                       const int* __restrict__ kidx, const float* __restrict__ protnT,
                       const float* __restrict__ taop, float* __restrict__ out) {
  __shared__ float sw[4][KTOP];
  __shared__ int   sj[4][KTOP];
  __shared__ float an[4][D];
  int lane = threadIdx.x & 63;
  int wv   = threadIdx.x >> 6;
  int i = blockIdx.x * 4 + wv;

  float v = -INFINITY; int jt = 0; bool mut = false;
  if (lane < KTOP) {
    v  = kval[(size_t)i * KTOP + lane];
    jt = kidx[(size_t)i * KTOP + lane];
    const int* oj = kidx + (size_t)jt * KTOP;
#pragma unroll
    for (int t = 0; t < KTOP; ++t) mut = mut || (oj[t] == i);
  }
  float lv = mut ? v : -INFINITY;
#pragma unroll
  for (int off = 1; off < 16; off <<= 1) lv = fmaxf(lv, __shfl_xor(lv, off));
  float wexp = mut ? expf(v - lv) : 0.f;    // self is always mutual -> z >= 1
  float z = wexp;
#pragma unroll
  for (int off = 1; off < 16; off <<= 1) z += __shfl_xor(z, off);
  if (lane < KTOP) { sw[wv][lane] = wexp / z; sj[wv][lane] = jt; }
  __syncthreads();

  float a0 = 0.f, a1 = 0.f;
#pragma unroll
  for (int t = 0; t < KTOP; ++t) {
    float wt = sw[wv][t];
    if (wt != 0.f) {
      int j = sj[wv][t];
      int xr = (j >> 7) * XROW + KSHOT + (j & 127);
      const float* qr = x + (size_t)xr * D;
      a0 += wt * qr[lane];
      a1 += wt * qr[64 + lane];
    }
  }
  float ss = a0 * a0 + a1 * a1;
#pragma unroll
  for (int off = 1; off < 64; off <<= 1) ss += __shfl_xor(ss, off);
  float rn = 1.0f / fmaxf(sqrtf(ss), EPSV);
  an[wv][lane]      = a0 * rn;
  an[wv][64 + lane] = a1 * rn;
  __syncthreads();

  float acc = 0.f;
#pragma unroll 8
  for (int d = 0; d < D; ++d) acc += an[wv][d] * protnT[d * NCLS + lane];
  out[(size_t)i * NCLS + lane] = taop[0] * acc;
}

// ---------------------------------------------------------------------------
extern "C" void kernel_launch(void* const* d_in, const int* in_sizes, int n_in,
                              void* d_out, int out_size, void* d_ws, size_t ws_size,
                              hipStream_t stream) {
  const float* x   = (const float*)d_in[0];
  const float* tao = (const float*)d_in[1];
  float* out = (float*)d_out;

  // workspace layout (floats), total ~14 MB
  float* qn     = (float*)d_ws;                       // 8192*128
  float* pkv    = qn + (size_t)M * D;                 // 8192*16*9
  int*   pki    = (int*)(pkv + (size_t)M * NPART * KTOP);
  float* kval   = (float*)(pki + (size_t)M * NPART * KTOP);  // 8192*9
  int*   kidx   = (int*)(kval + (size_t)M * KTOP);
  float* protnT = (float*)(kidx + (size_t)M * KTOP);  // 128*64

  k0_proto<<<NCLS, 64, 0, stream>>>(x, protnT);
  k1_qnorm<<<M / 4, 256, 0, stream>>>(x, qn);
  k2_topk<<<(M / BI) * SJ, TPB, 0, stream>>>(qn, pkv, pki);
  k_merge<<<M / 256, 256, 0, stream>>>(pkv, pki, kval, kidx);
  k3_out<<<M / 4, 256, 0, stream>>>(x, kval, kidx, protnT, tao, out);
}

// Round 10
// 422.411 us; speedup vs baseline: 3.0505x; 3.0505x over previous
//
#include <hip/hip_runtime.h>
#include <hip/hip_bf16.h>
#include <math.h>

// Problem constants (N_WAY=64, K_SHOT=5, Q_QUERY=128, D_FEAT=128)
#define M     8192      // n*q query rows
#define D     128       // feature dim
#define NCLS  64        // n classes
#define KSHOT 5
#define XROW  133       // (k+q) rows per class in x
#define KTOP  9
#define KC    12        // candidate count (bf16x3 err ~3e-7 << gap(9,12) ~9e-3)
#define EPSV  1e-8f

// k2m: MFMA candidate pass. Block = 64 i (4 waves x 16-i subs) x 1024 j (SJ=8).
#define SJ    8
#define JPB   (M / SJ)      // 1024 j per block
#define NTIL  (JPB / 16)    // 64 j-tiles of 16
#define NPART SJ            // 8 partial top-12 lists per i-row

typedef __attribute__((__ext_vector_type__(8))) short bf16v8;  // 8 bf16 = 4 VGPR
typedef __attribute__((__ext_vector_type__(4))) float f32v4;

// ---------------------------------------------------------------------------
// register-resident top-K with (value desc, index asc) tie-break, matching
// jax.lax.top_k set semantics. Fully unrolled -> static indexing -> VGPRs.
template <int KN>
__device__ __forceinline__ void topk_insert(float (&kv)[KN], int (&ki)[KN],
                                            float v, int j) {
  if (v > kv[KN - 1] || (v == kv[KN - 1] && j < ki[KN - 1])) {
    float cv = v; int cj = j;
#pragma unroll
    for (int t = 0; t < KN; ++t) {
      bool b = (cv > kv[t]) || (cv == kv[t] && cj < ki[t]);
      float tv = kv[t]; int ti_ = ki[t];
      kv[t] = b ? cv : tv;  ki[t] = b ? cj : ti_;
      cv   = b ? tv : cv;   cj   = b ? ti_ : cj;
    }
  }
}

// ---------------------------------------------------------------------------
__global__ void k0_proto(const float* __restrict__ x, float* __restrict__ protnT) {
  int c = blockIdx.x;
  int lane = threadIdx.x;
  const float* base = x + (size_t)(c * XROW) * D;
  float a0 = 0.f, a1 = 0.f;
#pragma unroll
  for (int s = 0; s < KSHOT; ++s) {
    a0 += base[s * D + lane];
    a1 += base[s * D + 64 + lane];
  }
  a0 *= 0.2f; a1 *= 0.2f;
  float ss = a0 * a0 + a1 * a1;
#pragma unroll
  for (int off = 1; off < 64; off <<= 1) ss += __shfl_xor(ss, off);
  float rn = 1.0f / fmaxf(sqrtf(ss), EPSV);
  protnT[lane * NCLS + c]        = a0 * rn;
  protnT[(lane + 64) * NCLS + c] = a1 * rn;
}

// ---------------------------------------------------------------------------
// k1: L2-normalize query rows -> qn (f32) and bf16 hi/lo split qh, ql.
__global__ void k1_qnorm(const float* __restrict__ x, float* __restrict__ qn,
                         short* __restrict__ qh, short* __restrict__ ql) {
  int lane = threadIdx.x & 63;
  int wv = threadIdx.x >> 6;
  int r = blockIdx.x * 4 + wv;
  int xr = (r >> 7) * XROW + KSHOT + (r & 127);
  const float* src = x + (size_t)xr * D;
  float v0 = src[lane], v1 = src[64 + lane];
  float ss = v0 * v0 + v1 * v1;
#pragma unroll
  for (int off = 1; off < 64; off <<= 1) ss += __shfl_xor(ss, off);
  float rn = 1.0f / fmaxf(sqrtf(ss), EPSV);
  float q0 = v0 * rn, q1 = v1 * rn;
  qn[(size_t)r * D + lane]      = q0;
  qn[(size_t)r * D + 64 + lane] = q1;
  __hip_bfloat16 h0 = __float2bfloat16(q0);
  __hip_bfloat16 h1 = __float2bfloat16(q1);
  __hip_bfloat16 l0 = __float2bfloat16(q0 - __bfloat162float(h0));
  __hip_bfloat16 l1 = __float2bfloat16(q1 - __bfloat162float(h1));
  qh[(size_t)r * D + lane]      = *(short*)&h0;
  qh[(size_t)r * D + 64 + lane] = *(short*)&h1;
  ql[(size_t)r * D + lane]      = *(short*)&l0;
  ql[(size_t)r * D + 64 + lane] = *(short*)&l1;
}

// ---------------------------------------------------------------------------
// k2m: bf16x3 MFMA candidate generation.
// mfma_f32_16x16x32_bf16, A = j-side (LDS tile, XOR-swizzled), B = i-side
// (persistent registers). acc = ah*bh + ah*bl + al*bh over 4 k-windows.
// D layout (m89-verified): i-col = lane&15, j-row = (lane>>4)*4 + reg.
__global__ __launch_bounds__(256) void
k2m(const short* __restrict__ qh, const short* __restrict__ ql,
    float* __restrict__ pkv, int* __restrict__ pki) {
  __shared__ __align__(16) short jh[16 * D];   // 4 KB j-tile hi
  __shared__ __align__(16) short jl[16 * D];   // 4 KB j-tile lo
  __shared__ float mv[4][16 * 4 * KC];         // per-wave merge scratch 12 KB
  __shared__ int   mi[4][16 * 4 * KC];         // 12 KB

  const int tid  = threadIdx.x;
  const int l    = tid & 63;
  const int w    = tid >> 6;
  const int ib   = blockIdx.x >> 3;        // 128 i-strips of 64
  const int js   = blockIdx.x & (SJ - 1);  // 8 j-splits
  const int i0   = ib * 64;
  const int j0s  = js * JPB;

  const bf16v8* qh8 = (const bf16v8*)qh;
  const bf16v8* ql8 = (const bf16v8*)ql;
  bf16v8* jh8 = (bf16v8*)jh;
  bf16v8* jl8 = (bf16v8*)jl;

  // ---- persistent i-side B fragments: lane's i-row, 4 k-windows ----
  const int irow = i0 + w * 16 + (l & 15);
  const int lg   = l >> 4;                 // k-group 0..3
  bf16v8 bh[4], bl[4];
#pragma unroll
  for (int kk = 0; kk < 4; ++kk) {
    bh[kk] = qh8[(size_t)irow * 16 + kk * 4 + lg];
    bl[kk] = ql8[(size_t)irow * 16 + kk * 4 + lg];
  }

  float kv[KC]; int ki[KC];
#pragma unroll
  for (int t = 0; t < KC; ++t) { kv[t] = -INFINITY; ki[t] = 0x7fffffff; }

  // stage indexing: thread t -> (row, chunk); XOR-swizzle chunk by row&7
  const int srow = tid >> 4;               // 0..15
  const int schk = tid & 15;               // 0..15
  const int sslot = srow * 16 + (schk ^ (srow & 7));

  // prefetch tile 0
  bf16v8 sa = qh8[(size_t)(j0s + srow) * 16 + schk];
  bf16v8 sb = ql8[(size_t)(j0s + srow) * 16 + schk];

  const int arow = l & 15;                 // A-frag j-row within tile

  for (int t = 0; t < NTIL; ++t) {
    __syncthreads();                       // previous tile's readers done
    jh8[sslot] = sa;
    jl8[sslot] = sb;
    __syncthreads();
    if (t + 1 < NTIL) {                    // prefetch next tile (hides L2 lat)
      sa = qh8[(size_t)(j0s + (t + 1) * 16 + srow) * 16 + schk];
      sb = ql8[(size_t)(j0s + (t + 1) * 16 + srow) * 16 + schk];
    }

    f32v4 acc = {0.f, 0.f, 0.f, 0.f};
#pragma unroll
    for (int kk = 0; kk < 4; ++kk) {
      int c2 = kk * 4 + lg;
      bf16v8 ah = jh8[arow * 16 + (c2 ^ (arow & 7))];
      bf16v8 al = jl8[arow * 16 + (c2 ^ (arow & 7))];
      acc = __builtin_amdgcn_mfma_f32_16x16x32_bf16(ah, bh[kk], acc, 0, 0, 0);
      acc = __builtin_amdgcn_mfma_f32_16x16x32_bf16(ah, bl[kk], acc, 0, 0, 0);
      acc = __builtin_amdgcn_mfma_f32_16x16x32_bf16(al, bh[kk], acc, 0, 0, 0);
    }

    const int jb = j0s + t * 16 + (l >> 4) * 4;   // lane's 4 j-rows
    topk_insert<KC>(kv, ki, acc[0], jb + 0);
    topk_insert<KC>(kv, ki, acc[1], jb + 1);
    topk_insert<KC>(kv, ki, acc[2], jb + 2);
    topk_insert<KC>(kv, ki, acc[3], jb + 3);
  }

  // ---- in-block merge: 4 lanes per i -> one top-12 per (i, block) ----
  __syncthreads();
#pragma unroll
  for (int t = 0; t < KC; ++t) {
    mv[w][l * KC + t] = kv[t];
    mi[w][l * KC + t] = ki[t];
  }
  __syncthreads();
  if (l < 16) {
    float fv[KC]; int fi[KC];
#pragma unroll
    for (int t = 0; t < KC; ++t) { fv[t] = -INFINITY; fi[t] = 0x7fffffff; }
#pragma unroll
    for (int g = 0; g < 4; ++g)
      for (int t = 0; t < KC; ++t)
        topk_insert<KC>(fv, fi, mv[w][(g * 16 + l) * KC + t],
                                 mi[w][(g * 16 + l) * KC + t]);
    int i = i0 + w * 16 + l;
    size_t base = ((size_t)i * NPART + js) * KC;
#pragma unroll
    for (int t = 0; t < KC; ++t) { pkv[base + t] = fv[t]; pki[base + t] = fi[t]; }
  }
}

// ---------------------------------------------------------------------------
// k_merge: per row, merge 8 partial top-12 lists -> 12 candidate indices.
__global__ void k_merge(const float* __restrict__ pkv, const int* __restrict__ pki,
                        int* __restrict__ cand) {
  int i = blockIdx.x * blockDim.x + threadIdx.x;
  float kv[KC]; int ki[KC];
#pragma unroll
  for (int t = 0; t < KC; ++t) { kv[t] = -INFINITY; ki[t] = 0x7fffffff; }
  const float* pv = pkv + (size_t)i * NPART * KC;
  const int*   pi = pki + (size_t)i * NPART * KC;
  for (int t = 0; t < NPART * KC; ++t) topk_insert<KC>(kv, ki, pv[t], pi[t]);
#pragma unroll
  for (int t = 0; t < KC; ++t) cand[(size_t)i * KC + t] = ki[t];
}

// ---------------------------------------------------------------------------
// k_rerank: exact fp32 dots for the 12 candidates; exact top-9 (jax tie-break).
// This firewall makes the bf16x3 candidate pass precision-irrelevant.
__global__ void k_rerank(const float* __restrict__ qn, const int* __restrict__ cand,
                         float* __restrict__ kval, int* __restrict__ kidx) {
  int lane = threadIdx.x & 63;
  int wv   = threadIdx.x >> 6;
  int i = blockIdx.x * 4 + wv;
  int jc = cand[(size_t)i * KC + (lane < KC ? lane : KC - 1)];
  const float4* qi = (const float4*)(qn + (size_t)i * D);
  const float4* qj = (const float4*)(qn + (size_t)jc * D);
  float dot = 0.f;
#pragma unroll
  for (int c = 0; c < 32; ++c) {
    float4 a = qi[c], b = qj[c];
    dot += a.x * b.x + a.y * b.y + a.z * b.z + a.w * b.w;
  }
  float kv[KTOP]; int ki[KTOP];
#pragma unroll
  for (int t = 0; t < KTOP; ++t) { kv[t] = -INFINITY; ki[t] = 0x7fffffff; }
#pragma unroll
  for (int t = 0; t < KC; ++t) {
    float v = __shfl(dot, t);
    int   jv = __shfl(jc, t);
    topk_insert<KTOP>(kv, ki, v, jv);
  }
  if (lane == 0) {
#pragma unroll
    for (int t = 0; t < KTOP; ++t) {
      kval[(size_t)i * KTOP + t] = kv[t];
      kidx[(size_t)i * KTOP + t] = ki[t];
    }
  }
}

// ---------------------------------------------------------------------------
// k3: mutual mask + softmax over <=9 entries + adapted query + normalize +
// project on normalized prototypes, scale by tao. One wave per query row.
__global__ void k3_out(const float* __restrict__ x, const float* __restrict__ kval,
                       const int* __restrict__ kidx, const float* __restrict__ protnT,
                       const float* __restrict__ taop, float* __restrict__ out) {
  __shared__ float sw[4][KTOP];
  __shared__ int   sj[4][KTOP];
  __shared__ float an[4][D];
  int lane = threadIdx.x & 63;
  int wv   = threadIdx.x >> 6;
  int i = blockIdx.x * 4 + wv;

  float v = -INFINITY; int jt = 0; bool mut = false;
  if (lane < KTOP) {
    v  = kval[(size_t)i * KTOP + lane];
    jt = kidx[(size_t)i * KTOP + lane];
    const int* oj = kidx + (size_t)jt * KTOP;
#pragma unroll
    for (int t = 0; t < KTOP; ++t) mut = mut || (oj[t] == i);
  }
  float lv = mut ? v : -INFINITY;
#pragma unroll
  for (int off = 1; off < 16; off <<= 1) lv = fmaxf(lv, __shfl_xor(lv, off));
  float wexp = mut ? expf(v - lv) : 0.f;    // self is always mutual -> z >= 1
  float z = wexp;
#pragma unroll
  for (int off = 1; off < 16; off <<= 1) z += __shfl_xor(z, off);
  if (lane < KTOP) { sw[wv][lane] = wexp / z; sj[wv][lane] = jt; }
  __syncthreads();

  float a0 = 0.f, a1 = 0.f;
#pragma unroll
  for (int t = 0; t < KTOP; ++t) {
    float wt = sw[wv][t];
    if (wt != 0.f) {
      int j = sj[wv][t];
      int xr = (j >> 7) * XROW + KSHOT + (j & 127);
      const float* qr = x + (size_t)xr * D;
      a0 += wt * qr[lane];
      a1 += wt * qr[64 + lane];
    }
  }
  float ss = a0 * a0 + a1 * a1;
#pragma unroll
  for (int off = 1; off < 64; off <<= 1) ss += __shfl_xor(ss, off);
  float rn = 1.0f / fmaxf(sqrtf(ss), EPSV);
  an[wv][lane]      = a0 * rn;
  an[wv][64 + lane] = a1 * rn;
  __syncthreads();

  float acc = 0.f;
#pragma unroll 8
  for (int d = 0; d < D; ++d) acc += an[wv][d] * protnT[d * NCLS + lane];
  out[(size_t)i * NCLS + lane] = taop[0] * acc;
}

// ---------------------------------------------------------------------------
extern "C" void kernel_launch(void* const* d_in, const int* in_sizes, int n_in,
                              void* d_out, int out_size, void* d_ws, size_t ws_size,
                              hipStream_t stream) {
  const float* x   = (const float*)d_in[0];
  const float* tao = (const float*)d_in[1];
  float* out = (float*)d_out;

  // workspace layout, ~15.5 MB total
  float* qn   = (float*)d_ws;                         // 8192*128 f32 (4 MB)
  short* qh   = (short*)(qn + (size_t)M * D);         // 2 MB bf16 hi
  short* ql   = qh + (size_t)M * D;                   // 2 MB bf16 lo
  float* pkv  = (float*)(ql + (size_t)M * D);         // 8192*8*12 (3 MB)
  int*   pki  = (int*)(pkv + (size_t)M * NPART * KC); // 3 MB
  int*   cand = pki + (size_t)M * NPART * KC;         // 8192*12 (0.4 MB)
  float* kval = (float*)(cand + (size_t)M * KC);      // 8192*9
  int*   kidx = (int*)(kval + (size_t)M * KTOP);
  float* protnT = (float*)(kidx + (size_t)M * KTOP);  // 128*64

  k0_proto<<<NCLS, 64, 0, stream>>>(x, protnT);
  k1_qnorm<<<M / 4, 256, 0, stream>>>(x, qn, qh, ql);
  k2m<<<(M / 64) * SJ, 256, 0, stream>>>(qh, ql, pkv, pki);
  k_merge<<<M / 256, 256, 0, stream>>>(pkv, pki, cand);
  k_rerank<<<M / 4, 256, 0, stream>>>(qn, cand, kval, kidx);
  k3_out<<<M / 4, 256, 0, stream>>>(x, kval, kidx, protnT, tao, out);
}